// Round 1
// 192.668 us; speedup vs baseline: 1.0601x; 1.0601x over previous
//
#include <hip/hip_runtime.h>
#include <hip/hip_bf16.h>
#include <stdint.h>

// Problem sizes (compile-time)
static constexpr int BATCH = 32768;
static constexpr int DIN   = 512;
static constexpr int DHID  = 1024;
static constexpr int DOUT  = 2048;

typedef __bf16 bf16x8 __attribute__((ext_vector_type(8)));
typedef float  f32x4  __attribute__((ext_vector_type(4)));

// fp32 -> bf16 round-to-nearest-even
__device__ __forceinline__ unsigned short f2bf(float f) {
    unsigned int u = __float_as_uint(f);
    u += 0x7FFFu + ((u >> 16) & 1u);
    return (unsigned short)(u >> 16);
}

// async global->LDS, 16B per lane. LDS dest = WAVE-uniform base + 16*(lane&63).
__device__ __forceinline__ void gload_lds16(const void* g, void* l) {
    __builtin_amdgcn_global_load_lds((__attribute__((address_space(1))) void*)g,
                                     (__attribute__((address_space(3))) void*)l,
                                     16, 0, 0);
}

// ===========================================================================
// scores = x @ W^T + b' (algebraic fusion; absmax 0.03125 measured)
//   W[o,i] = sum_h w2[o,h] w1[h,i];  b'[o] = dot(b1, w2[o,:]) + b2[o]
// r15: gemmS rewritten as the 256^2 8-phase counted-vmcnt template
// (T3+T4+T5; m201 structure). prep/gemmW/reduce unchanged from r14.
// ===========================================================================

// ---------------------------------------------------------------------------
// prep: one dispatch, region-decoded by blockIdx.x (unchanged)
// ---------------------------------------------------------------------------
__global__ __launch_bounds__(256) void prep_kernel(
    const float* __restrict__ w1, const float4* __restrict__ w2f,
    const float4* __restrict__ xf, const float* __restrict__ b1,
    const float* __restrict__ b2,
    unsigned short* __restrict__ w1t, ushort4* __restrict__ w2b,
    ushort4* __restrict__ xb, float* __restrict__ bp) {
    const int blk = blockIdx.x;
    const int t   = threadIdx.x;
    if (blk < 512) {
        __shared__ float tile[32][33];
        const int tileI = blk & 15;
        const int tileH = blk >> 4;
        const int iBase = tileI * 32, hBase = tileH * 32;
        const int col = t & 31, rowq = t >> 5;
#pragma unroll
        for (int p = 0; p < 4; ++p) {
            const int row = p * 8 + rowq;
            tile[row][col] = w1[(size_t)(hBase + row) * DIN + iBase + col];
        }
        __syncthreads();
#pragma unroll
        for (int p = 0; p < 4; ++p) {
            const int row = p * 8 + rowq;
            w1t[(size_t)(iBase + row) * DHID + hBase + col] = f2bf(tile[col][row]);
        }
    } else if (blk < 2560) {
        __shared__ float wsum[4];
        const int o = blk - 512;
        const size_t g = (size_t)o * 256 + t;
        float4 v = w2f[g];
        ushort4 ob;
        ob.x = f2bf(v.x); ob.y = f2bf(v.y); ob.z = f2bf(v.z); ob.w = f2bf(v.w);
        w2b[g] = ob;
        float4 bv = ((const float4*)b1)[t];
        float s = v.x * bv.x + v.y * bv.y + v.z * bv.z + v.w * bv.w;
#pragma unroll
        for (int off = 1; off < 64; off <<= 1) s += __shfl_xor(s, off);
        if ((t & 63) == 0) wsum[t >> 6] = s;
        __syncthreads();
        if (t == 0) bp[o] = wsum[0] + wsum[1] + wsum[2] + wsum[3] + b2[o];
    } else {
        const size_t g = (size_t)(blk - 2560) * 256 + t;
        float4 v = xf[g];
        ushort4 o;
        o.x = f2bf(v.x); o.y = f2bf(v.y); o.z = f2bf(v.z); o.w = f2bf(v.w);
        xb[g] = o;
    }
}

// ---------------------------------------------------------------------------
// gemmW: W[o,i] = sum_h w2b[o,h] * w1t[i,h]. (unchanged)
// ---------------------------------------------------------------------------
__global__ __launch_bounds__(256) void gemmW_kernel(
    const unsigned short* __restrict__ A,
    const unsigned short* __restrict__ Bw,
    unsigned short* __restrict__ W) {
    constexpr int K = DHID;
    __shared__ __align__(16) unsigned short sA[64 * 128];
    __shared__ __align__(16) unsigned short sB[64 * 128];

    const int tid  = threadIdx.x;
    const int lane = tid & 63;
    const int wid  = tid >> 6;
    const int wr = wid >> 1, wc = wid & 1;
    const int r = lane & 15, q = lane >> 4;
    const int blockN = blockIdx.x * 64;
    const int blockM = blockIdx.y * 64;

    const int chKey = (tid & 15) ^ ((tid >> 4) & 15);
    const size_t aBase = (size_t)(blockM + (tid >> 4)) * K + chKey * 8;
    const size_t bBase = (size_t)(blockN + (tid >> 4)) * K + chKey * 8;

    f32x4 acc[2][2];
#pragma unroll
    for (int mt = 0; mt < 2; ++mt)
#pragma unroll
        for (int nt = 0; nt < 2; ++nt) { f32x4 z = {0.f, 0.f, 0.f, 0.f}; acc[mt][nt] = z; }

    for (int k0 = 0; k0 < K; k0 += 128) {
#pragma unroll
        for (int j = 0; j < 4; ++j) {
            gload_lds16(A  + aBase + (size_t)j * 16 * K + k0, sA + j * 2048 + wid * 512);
            gload_lds16(Bw + bBase + (size_t)j * 16 * K + k0, sB + j * 2048 + wid * 512);
        }
        __syncthreads();
#pragma unroll
        for (int ks = 0; ks < 4; ++ks) {
            const int ch = ((ks << 2) + q) ^ r;
            bf16x8 af[2], bf[2];
#pragma unroll
            for (int mt = 0; mt < 2; ++mt) af[mt] = *(const bf16x8*)&sA[(wr * 32 + mt * 16 + r) * 128 + ch * 8];
#pragma unroll
            for (int nt = 0; nt < 2; ++nt) bf[nt] = *(const bf16x8*)&sB[(wc * 32 + nt * 16 + r) * 128 + ch * 8];
#pragma unroll
            for (int mt = 0; mt < 2; ++mt)
#pragma unroll
                for (int nt = 0; nt < 2; ++nt)
                    acc[mt][nt] = __builtin_amdgcn_mfma_f32_16x16x32_bf16(af[mt], bf[nt], acc[mt][nt], 0, 0, 0);
        }
        __syncthreads();
    }

#pragma unroll
    for (int mt = 0; mt < 2; ++mt) {
        const int row0 = blockM + wr * 32 + mt * 16 + q * 4;
#pragma unroll
        for (int nt = 0; nt < 2; ++nt) {
            const int col = blockN + wc * 32 + nt * 16 + r;
#pragma unroll
            for (int reg = 0; reg < 4; ++reg)
                W[(size_t)(row0 + reg) * DIN + col] = f2bf(acc[mt][nt][reg]);
        }
    }
}

// ---------------------------------------------------------------------------
// gemmS r15: scores = xb @ W^T + b', fused row-max.
// 256x256 tile, BK=64, 512 threads (2Mx4N waves), 128 KiB LDS.
// 8-phase schedule, counted vmcnt(6) at phases 4/8 only (T3+T4), setprio (T5).
//
// LDS (shorts): base(buf,isB,kh) = buf*32768 + isB*16384 + kh*8192.
// Stage unit = 256 rows x 32 k (16 KB) = 2 gload_lds16/thread.
//   slot s = j*512+tid -> row s>>2, chunk s&3; LDS(row,c) holds global
//   chunk c ^ ((row>>1)&3)  (pre-swizzled SOURCE, linear dest - rule #21).
//   ds_read_b128 frag: chunk q^((r>>1)&3) -> 2-way bank alias = free (m136).
// Per-phase retirement (verified): phase p stages the region last-read at
// p-1; vmcnt(6) leaves 3 units in flight, forcing lands >=2 phases pre-read.
//   P1 ds A(b0,k0,m0-3)+B(b0,k0) | stage b1.Akhi(t1)   | MFMA m0-3
//   P2 ds A(b0,k0,m4-7)          | stage b0.Bklo(t+2)  | MFMA m4-7
//   P3 ds A(b0,k1,m0-3)+B(b0,k1) | stage b0.Aklo(t+2)  | MFMA m0-3
//   P4 ds A(b0,k1,m4-7)          | stage b0.Bkhi(t+2) vmcnt(6) | MFMA m4-7
//   P5-P8: same with buf1 / stages b0.Akhi(t+2), b1.{Bklo,Aklo,Bkhi}(t+3)
// ---------------------------------------------------------------------------
__global__ __launch_bounds__(512, 2) void gemmS_kernel(
    const unsigned short* __restrict__ A,   // xb bf16 [BATCH, DIN]
    const unsigned short* __restrict__ Bw,  // W bf16 [DOUT, DIN]
    const float* __restrict__ bp,           // b' [DOUT]
    float* __restrict__ partials) {         // [BATCH, 32]
    constexpr int K = DIN;                   // 512, NKT = 8 K-tiles of 64
    __shared__ __align__(16) unsigned short lds[65536];  // 128 KB

    const int tid  = threadIdx.x;            // 0..511
    const int lane = tid & 63;
    const int wid  = tid >> 6;               // 0..7
    const int wr   = wid >> 2;               // 0..1 (M)
    const int wc   = wid & 3;                // 0..3 (N)
    const int r    = lane & 15, q = lane >> 4;

    // XCD-banded grid: 1024 blocks = 8 xcd x (16 M x 8 N); nwg%8==0 ok.
    const int g    = blockIdx.x;
    const int xcd  = g & 7;
    const int i    = g >> 3;                 // 0..127
    const int mIdx = xcd * 16 + (i >> 3);    // 0..127
    const int nIdx = i & 7;                  // 0..7
    const int blockM = mIdx * 256;
    const int blockN = nIdx * 256;

    // staging addresses (pre-swizzled global source)
    const int sRow = tid >> 2;               // 0..127 (j=1 adds 128)
    const int swz  = (tid & 3) ^ ((tid >> 3) & 3);
    const unsigned short* aSrc = A  + (size_t)(blockM + sRow) * K + swz * 8;
    const unsigned short* bSrc = Bw + (size_t)(blockN + sRow) * K + swz * 8;
    unsigned short* ldsW = lds + wid * 512;  // wave-uniform stage base

#define STAGE(srcPtr, isB, buf, kh, kt) do {                                    \
    gload_lds16((srcPtr) + (kt) * 64 + (kh) * 32,                               \
                ldsW + (buf) * 32768 + (isB) * 16384 + (kh) * 8192);            \
    gload_lds16((srcPtr) + 128 * K + (kt) * 64 + (kh) * 32,                     \
                ldsW + (buf) * 32768 + (isB) * 16384 + (kh) * 8192 + 4096);     \
} while (0)

    // fragment read bases (swizzled chunk)
    const int rsw  = (r >> 1) & 3;
    const int fOff = (q ^ rsw) * 8;
    const unsigned short* ldsAf = lds + (wr * 128 + r) * 32 + fOff;
    const unsigned short* ldsBf = lds + 16384 + (wc * 64 + r) * 32 + fOff;

    f32x4 acc[8][4];
#pragma unroll
    for (int mt = 0; mt < 8; ++mt)
#pragma unroll
        for (int nt = 0; nt < 4; ++nt) { f32x4 z = {0.f, 0.f, 0.f, 0.f}; acc[mt][nt] = z; }
    bf16x8 af[4], bfr[4];

#define LDA(buf, ks, mg) do {                                                   \
    const unsigned short* p_ = ldsAf + (buf) * 32768 + (ks) * 8192 + (mg) * 2048; \
    af[0] = *(const bf16x8*)(p_);                                               \
    af[1] = *(const bf16x8*)(p_ + 512);                                         \
    af[2] = *(const bf16x8*)(p_ + 1024);                                        \
    af[3] = *(const bf16x8*)(p_ + 1536);                                        \
} while (0)
#define LDB(buf, ks) do {                                                       \
    const unsigned short* p_ = ldsBf + (buf) * 32768 + (ks) * 8192;             \
    bfr[0] = *(const bf16x8*)(p_);                                              \
    bfr[1] = *(const bf16x8*)(p_ + 512);                                        \
    bfr[2] = *(const bf16x8*)(p_ + 1024);                                       \
    bfr[3] = *(const bf16x8*)(p_ + 1536);                                       \
} while (0)
#define MM(mg) do {                                                             \
    __builtin_amdgcn_s_setprio(1);                                              \
    _Pragma("unroll") for (int m_ = 0; m_ < 4; ++m_)                            \
    _Pragma("unroll") for (int n_ = 0; n_ < 4; ++n_)                            \
        acc[(mg) * 4 + m_][n_] = __builtin_amdgcn_mfma_f32_16x16x32_bf16(       \
            af[m_], bfr[n_], acc[(mg) * 4 + m_][n_], 0, 0, 0);                  \
    __builtin_amdgcn_s_setprio(0);                                              \
} while (0)
#define BAR()   __builtin_amdgcn_s_barrier()
#define LGKM0() asm volatile("s_waitcnt lgkmcnt(0)" ::: "memory")
#define VMC(n)  asm volatile("s_waitcnt vmcnt(" #n ")" ::: "memory")

    // Prologue: tile0 -> buf0 (4 units), tile1 -> buf1 (3 units); land tile0.
    STAGE(bSrc, 1, 0, 0, 0);
    STAGE(aSrc, 0, 0, 0, 0);
    STAGE(bSrc, 1, 0, 1, 0);
    STAGE(aSrc, 0, 0, 1, 0);
    STAGE(bSrc, 1, 1, 0, 1);
    STAGE(aSrc, 0, 1, 0, 1);
    STAGE(bSrc, 1, 1, 1, 1);
    VMC(6);
    BAR();

#pragma unroll 1
    for (int it = 0; it < 3; ++it) {
        const int t1 = 2 * it + 1, n0 = 2 * it + 2, n1 = 2 * it + 3;
        // P1
        LDA(0, 0, 0); LDB(0, 0); STAGE(aSrc, 0, 1, 1, t1);
        BAR(); LGKM0(); MM(0); BAR();
        // P2
        LDA(0, 0, 1); STAGE(bSrc, 1, 0, 0, n0);
        BAR(); LGKM0(); MM(1); BAR();
        // P3
        LDA(0, 1, 0); LDB(0, 1); STAGE(aSrc, 0, 0, 0, n0);
        BAR(); LGKM0(); MM(0); BAR();
        // P4
        LDA(0, 1, 1); STAGE(bSrc, 1, 0, 1, n0); VMC(6);
        BAR(); LGKM0(); MM(1); BAR();
        // P5
        LDA(1, 0, 0); LDB(1, 0); STAGE(aSrc, 0, 0, 1, n0);
        BAR(); LGKM0(); MM(0); BAR();
        // P6
        LDA(1, 0, 1); STAGE(bSrc, 1, 1, 0, n1);
        BAR(); LGKM0(); MM(1); BAR();
        // P7
        LDA(1, 1, 0); LDB(1, 1); STAGE(aSrc, 0, 1, 0, n1);
        BAR(); LGKM0(); MM(0); BAR();
        // P8
        LDA(1, 1, 1); STAGE(bSrc, 1, 1, 1, n1); VMC(6);
        BAR(); LGKM0(); MM(1); BAR();
    }
    // Peeled last iteration (tiles 6,7): only P1's stage remains; full drain
    // at P4 (skipped stages would leave vmcnt(6) not forcing tile7's lands).
    LDA(0, 0, 0); LDB(0, 0); STAGE(aSrc, 0, 1, 1, 7);
    BAR(); LGKM0(); MM(0); BAR();
    LDA(0, 0, 1);
    BAR(); LGKM0(); MM(1); BAR();
    LDA(0, 1, 0); LDB(0, 1);
    BAR(); LGKM0(); MM(0); BAR();
    LDA(0, 1, 1); VMC(0);
    BAR(); LGKM0(); MM(1); BAR();
    LDA(1, 0, 0); LDB(1, 0);
    BAR(); LGKM0(); MM(0); BAR();
    LDA(1, 0, 1);
    BAR(); LGKM0(); MM(1); BAR();
    LDA(1, 1, 0); LDB(1, 1);
    BAR(); LGKM0(); MM(0); BAR();
    LDA(1, 1, 1);
    BAR(); LGKM0(); MM(1);

#undef STAGE
#undef LDA
#undef LDB
#undef MM
#undef BAR
#undef LGKM0
#undef VMC

    // Epilogue: +b', max over the wave's 64 cols (nt then 16-lane r-reduce).
    // C/D: col = r (N side), row = q*4+reg (M side).
    const int colBase = blockN + wc * 64;
    float bv[4];
#pragma unroll
    for (int nt = 0; nt < 4; ++nt) bv[nt] = bp[colBase + nt * 16 + r];

#pragma unroll
    for (int mt = 0; mt < 8; ++mt) {
#pragma unroll
        for (int reg = 0; reg < 4; ++reg) {
            float v = fmaxf(fmaxf(acc[mt][0][reg] + bv[0], acc[mt][1][reg] + bv[1]),
                            fmaxf(acc[mt][2][reg] + bv[2], acc[mt][3][reg] + bv[3]));
#pragma unroll
            for (int off = 1; off < 16; off <<= 1)
                v = fmaxf(v, __shfl_xor(v, off));
            if (r == 0) {
                const int row = blockM + wr * 128 + mt * 16 + q * 4 + reg;
                partials[(size_t)row * 32 + nIdx * 4 + wc] = v;
            }
        }
    }
}

// ---------------------------------------------------------------------------
// reduce: 32 partials per row -> final max (unchanged)
// ---------------------------------------------------------------------------
__global__ __launch_bounds__(256) void reduce_kernel(
    const float4* __restrict__ partials, float* __restrict__ out) {
    const int row = blockIdx.x * blockDim.x + threadIdx.x;
    const float4* p = partials + (size_t)row * 8;
    float m = -INFINITY;
#pragma unroll
    for (int i = 0; i < 8; ++i) {
        float4 v = p[i];
        m = fmaxf(m, fmaxf(fmaxf(v.x, v.y), fmaxf(v.z, v.w)));
    }
    out[row] = m;
}

// ---------------------------------------------------------------------------
extern "C" void kernel_launch(void* const* d_in, const int* in_sizes, int n_in,
                              void* d_out, int out_size, void* d_ws, size_t ws_size,
                              hipStream_t stream) {
    const float* x   = (const float*)d_in[0];
    const float* l1w = (const float*)d_in[1];
    const float* l1b = (const float*)d_in[2];
    const float* w2  = (const float*)d_in[3];
    const float* b2  = (const float*)d_in[4];
    float* out = (float*)d_out;

    char* ws = (char*)d_ws;
    unsigned short* w1t = (unsigned short*)(ws);                 //  1 MB  w1^T bf16 [512,1024]
    unsigned short* w2b = (unsigned short*)(ws + 1048576);       //  4 MB  w2 bf16 [2048,1024]
    unsigned short* Wb  = (unsigned short*)(ws + 5242880);       //  2 MB  W bf16 [2048,512]
    float* bp           = (float*)(ws + 7340032);                //  8 KB  b' fp32 [2048]
    unsigned short* xb  = (unsigned short*)(ws + 7348224);       // 32 MB  x bf16 [32768,512]
    float* partials     = (float*)(ws + 40902656);               //  4 MB  [BATCH,32]

    // 1) fused pre-work: w1 transpose + w2 cvt(+bgemv) + x cvt
    prep_kernel<<<18944, 256, 0, stream>>>(
        l1w, (const float4*)w2, (const float4*)x, l1b, b2,
        w1t, (ushort4*)w2b, (ushort4*)xb, bp);

    // 2) W = w2b @ w1t^T  [2048, 512]
    gemmW_kernel<<<dim3(DIN / 64, DOUT / 64), 256, 0, stream>>>(w2b, w1t, Wb);

    // 3) scores = xb @ W^T + b', fused row-max (256^2 8-phase, 1024 blocks)
    gemmS_kernel<<<1024, 512, 0, stream>>>(xb, Wb, bp, partials);

    // 4) final max over 32 partials per row
    reduce_kernel<<<BATCH / 256, 256, 0, stream>>>((const float4*)partials, out);
}